// Round 9
// baseline (211.984 us; speedup 1.0000x reference)
//
#include <hip/hip_runtime.h>

#define TAU_INV 2.0f  // 1/0.5

typedef unsigned short u16;
typedef short bf16x8 __attribute__((ext_vector_type(8)));
typedef float f32x4 __attribute__((ext_vector_type(4)));
typedef u16 u16x4v __attribute__((ext_vector_type(4)));
typedef u16 u16x8v __attribute__((ext_vector_type(8)));

typedef __attribute__((address_space(1))) const void GASV;
typedef __attribute__((address_space(3))) void LASV;
#define GLOAD16(gp, lp) __builtin_amdgcn_global_load_lds((GASV*)(gp), (LASV*)(lp), 16, 0, 0)

__device__ __forceinline__ u16 f2bf(float f) {
  unsigned u = __float_as_uint(f);
  u += 0x7FFFu + ((u >> 16) & 1u);  // round-to-nearest-even
  return (u16)(u >> 16);
}

// ---------- kernel 1: x cast [0,588) + W mid-band cast [588,624). No LDS. ----------
__global__ __launch_bounds__(256) void k_cast(const float* __restrict__ x,
                                              u16* __restrict__ xb,
                                              const float* __restrict__ W,
                                              u16* __restrict__ Weff) {
  const int bid = blockIdx.x;
  const int tid = threadIdx.x;
  if (bid < 588) {  // x f32 -> bf16: 588 * 4 * 2048 = 4,816,896
#pragma unroll
    for (int it = 0; it < 4; ++it) {
      const int i = ((bid * 4 + it) * 256 + tid) * 8;
      float4 v0 = *(const float4*)(x + i);
      float4 v1 = *(const float4*)(x + i + 4);
      u16x8v o;
      o[0] = f2bf(v0.x); o[1] = f2bf(v0.y); o[2] = f2bf(v0.z); o[3] = f2bf(v0.w);
      o[4] = f2bf(v1.x); o[5] = f2bf(v1.y); o[6] = f2bf(v1.z); o[7] = f2bf(v1.w);
      *(u16x8v*)(xb + i) = o;
    }
    return;
  }
  // W middle band rows 768..1535: Weff = bf16(W)
  const int base = 589824 + (bid - 588) * 16384;
#pragma unroll
  for (int it = 0; it < 8; ++it) {
    const int i = base + (it * 256 + tid) * 8;
    float4 v0 = *(const float4*)(W + i);
    float4 v1 = *(const float4*)(W + i + 4);
    u16x8v o;
    o[0] = f2bf(v0.x); o[1] = f2bf(v0.y); o[2] = f2bf(v0.z); o[3] = f2bf(v0.w);
    o[4] = f2bf(v1.x); o[5] = f2bf(v1.y); o[6] = f2bf(v1.z); o[7] = f2bf(v1.w);
    *(u16x8v*)(Weff + i) = o;
  }
}

// ---------- kernel 2: dW bands with IN-BLOCK scales (72 blocks) ----------
// Per block: compute its branch's 10 gate-softmax/Frobenius scales (L2-resident
// reads, ~1MB), then single-barrier staged MFMA: all K=160 of both operands in
// LDS (stride 168 kills frag conflicts), 80 MFMAs straight.
__global__ __launch_bounds__(256) void k_dwall(
    const float* __restrict__ Aq, const float* __restrict__ Bq,
    const float* __restrict__ Av, const float* __restrict__ Bv,
    const float* __restrict__ lq, const float* __restrict__ lv,
    const float* __restrict__ W, u16* __restrict__ Weff) {
  __shared__ u16 As[128 * 168];  // [d][168]  (160 data + 8 pad)
  __shared__ u16 Bs[128 * 168];  // [c][168]
  __shared__ float sSum[20][4];
  __shared__ float sScale[16];
  const int bid = blockIdx.x;
  const int tid = threadIdx.x;
  const int br = bid / 36, t36 = bid % 36;
  const int tm = t36 / 6, tn = t36 % 6;
  const float* __restrict__ A = br ? Av : Aq;   // [160][768] = [10][16][768]
  const float* __restrict__ B = br ? Bv : Bq;   // [10][768][16]
  const float* __restrict__ lg = br ? lv : lq;  // [10]
  const int d0 = tm * 128, c0 = tn * 128;
  const int rowbase = br ? 1536 : 0;
  const int lane = tid & 63, w = tid >> 6, wm = w >> 1, wn = w & 1;
  const int lr = lane & 15, kb = lane >> 4;

  // ---- in-block scales: 20 sum-of-squares reductions (10 A tasks, 10 B tasks)
#pragma unroll 1
  for (int g = 0; g < 20; ++g) {
    const float4* P = (const float4*)((g < 10 ? A + g * 12288 : B + (g - 10) * 12288));
    float s = 0.f;
    for (int i = tid; i < 3072; i += 256) {
      float4 v = P[i];
      s += v.x * v.x + v.y * v.y + v.z * v.z + v.w * v.w;
    }
    for (int off = 32; off; off >>= 1) s += __shfl_down(s, off);
    if (lane == 0) sSum[g][w] = s;
  }
  __syncthreads();
  if (tid < 10) {
    float sA = sSum[tid][0] + sSum[tid][1] + sSum[tid][2] + sSum[tid][3];
    float sB = sSum[tid + 10][0] + sSum[tid + 10][1] + sSum[tid + 10][2] + sSum[tid + 10][3];
    float mx = -1e30f;
    for (int j = 0; j < 10; ++j) mx = fmaxf(mx, lg[j] * TAU_INV);
    float den = 0.f;
    for (int j = 0; j < 10; ++j) den += __expf(lg[j] * TAU_INV - mx);
    float num = __expf(lg[tid] * TAU_INV - mx);
    sScale[tid] = (num / den) * rsqrtf(sA) * rsqrtf(sB);
  }
  __syncthreads();

  // ---- stage As[d][k] = B[t][d0+d][r] * s[t],  k = t*16+r  (5120 float4s)
  for (int j = 0; j < 20; ++j) {
    int f = j * 256 + tid;
    int d = f / 40;
    int k = (f % 40) * 4;
    int t = k >> 4, r = k & 15;
    float4 v = *(const float4*)(B + (t * 768 + d0 + d) * 16 + r);
    float s = sScale[t];
    u16x4v o;
    o[0] = f2bf(v.x * s); o[1] = f2bf(v.y * s);
    o[2] = f2bf(v.z * s); o[3] = f2bf(v.w * s);
    *(u16x4v*)(As + d * 168 + k) = o;
  }
  // ---- stage Bs[c][k] = A[k][c0+c]  (transpose at write)
  for (int j = 0; j < 20; ++j) {
    int f = j * 256 + tid;
    int k = f / 32;
    int c = (f % 32) * 4;
    float4 v = *(const float4*)(A + k * 768 + c0 + c);
    Bs[(c + 0) * 168 + k] = f2bf(v.x);
    Bs[(c + 1) * 168 + k] = f2bf(v.y);
    Bs[(c + 2) * 168 + k] = f2bf(v.z);
    Bs[(c + 3) * 168 + k] = f2bf(v.w);
  }
  __syncthreads();

  f32x4 acc[4][4];
#pragma unroll
  for (int i = 0; i < 4; ++i)
#pragma unroll
    for (int j = 0; j < 4; ++j)
#pragma unroll
      for (int e = 0; e < 4; ++e) acc[i][j][e] = 0.f;

#pragma unroll
  for (int kt = 0; kt < 5; ++kt) {
    bf16x8 a[4], b[4];
#pragma unroll
    for (int i = 0; i < 4; ++i)
      a[i] = *(const bf16x8*)(As + (wm * 64 + i * 16 + lr) * 168 + kt * 32 + kb * 8);
#pragma unroll
    for (int j = 0; j < 4; ++j)
      b[j] = *(const bf16x8*)(Bs + (wn * 64 + j * 16 + lr) * 168 + kt * 32 + kb * 8);
#pragma unroll
    for (int i = 0; i < 4; ++i)
#pragma unroll
      for (int j = 0; j < 4; ++j)
        acc[i][j] = __builtin_amdgcn_mfma_f32_16x16x32_bf16(a[i], b[j], acc[i][j], 0, 0, 0);
  }
#pragma unroll
  for (int i = 0; i < 4; ++i)
#pragma unroll
    for (int jn = 0; jn < 4; ++jn)
#pragma unroll
      for (int j = 0; j < 4; ++j) {
        int row = rowbase + d0 + wm * 64 + i * 16 + kb * 4 + j;
        int col = c0 + wn * 64 + jn * 16 + lr;
        int g = row * 768 + col;
        Weff[g] = f2bf(W[g] + acc[i][jn][j]);
      }
}

// ---------- kernel 3: main GEMM, 256x256 8-phase (T2+T3+T4+T5), race-fixed staging ----------
// Hazard ledger (per K-tile, regions delimited by barriers):
//   B buf[cur] reads complete block-wide by BAR5 -> STG_B(cur,kt+2,*) after BAR5.
//   A buf[cur] reads complete block-wide by BAR7 -> STG_A(cur,kt+2,0) after BAR7,
//   STG_A(cur,kt+2,1) after BAR9.  vmcnt(8) at tile top forces the 8 loads
//   issued 2 iters ago complete.
__global__ __launch_bounds__(512, 2) void k_gemm(
    const u16* __restrict__ Xb,     // [6400][768] bf16 (rows >=6272 are pad)
    const u16* __restrict__ Wb,     // [2304][768] bf16
    const float* __restrict__ bias, // [2304]
    float* __restrict__ out) {      // [6272][2304]
  // bijective XCD remap: nwg=225, q=28, r=1
  const int b = blockIdx.x;
  const int xcd = b & 7, sub = b >> 3;
  const int wgid = (xcd == 0) ? sub : (29 + (xcd - 1) * 28 + sub);
  const int tn = wgid % 9, tm = wgid / 9;
  const int m0 = tm * 256, n0 = tn * 256;
  __shared__ char lds[131072];  // A: [0,64K) B: [64K,128K)
  const int tid = threadIdx.x;
  const int lane = tid & 63;
  const int w = tid >> 6, wm = w >> 2, wn = w & 3;
  const int lr = lane & 15, kb = lane >> 4;
  const int cs0 = ((kb ^ (lr & 7)) << 4);
  const int cs1 = (((4 + kb) ^ (lr & 7)) << 4);
  const int arow = (wm * 128 + lr) << 7;
  const int brow = (wn * 64 + lr) << 7;
  const int r0 = tid >> 3;
  const int cb0 = (((tid & 7) ^ (r0 & 7)) << 3);  // u16 units
  const u16* pA = Xb + (m0 + r0) * 768 + cb0;
  const u16* pB = Wb + (n0 + r0) * 768 + cb0;
  const int wb = (tid >> 6) << 10;

  f32x4 acc[8][4];
#pragma unroll
  for (int i = 0; i < 8; ++i)
#pragma unroll
    for (int j = 0; j < 4; ++j)
#pragma unroll
      for (int e = 0; e < 4; ++e) acc[i][j][e] = 0.f;

#define STG_A(buf, kt, h)                                                        \
  {                                                                              \
    GLOAD16(pA + ((h)*128 + 0) * 768 + (kt)*64, lds + (buf)*32768 + (h)*16384 + 0 + wb);    \
    GLOAD16(pA + ((h)*128 + 64) * 768 + (kt)*64, lds + (buf)*32768 + (h)*16384 + 8192 + wb);\
  }
#define STG_B(buf, kt, h)                                                        \
  {                                                                              \
    GLOAD16(pB + ((h)*128 + 0) * 768 + (kt)*64, lds + 65536 + (buf)*32768 + (h)*16384 + 0 + wb);    \
    GLOAD16(pB + ((h)*128 + 64) * 768 + (kt)*64, lds + 65536 + (buf)*32768 + (h)*16384 + 8192 + wb);\
  }
#define LDA8(buf, mh)                                                            \
  {                                                                              \
    const char* p_ = lds + (buf)*32768 + arow + (mh)*8192;                       \
    a[0] = *(const bf16x8*)(p_ + 0 * 2048 + cs0);                                \
    a[1] = *(const bf16x8*)(p_ + 0 * 2048 + cs1);                                \
    a[2] = *(const bf16x8*)(p_ + 1 * 2048 + cs0);                                \
    a[3] = *(const bf16x8*)(p_ + 1 * 2048 + cs1);                                \
    a[4] = *(const bf16x8*)(p_ + 2 * 2048 + cs0);                                \
    a[5] = *(const bf16x8*)(p_ + 2 * 2048 + cs1);                                \
    a[6] = *(const bf16x8*)(p_ + 3 * 2048 + cs0);                                \
    a[7] = *(const bf16x8*)(p_ + 3 * 2048 + cs1);                                \
  }
#define LDB4(dst, buf, nh)                                                       \
  {                                                                              \
    const char* p_ = lds + 65536 + (buf)*32768 + brow + (nh)*4096;               \
    dst[0] = *(const bf16x8*)(p_ + 0 * 2048 + cs0);                              \
    dst[1] = *(const bf16x8*)(p_ + 0 * 2048 + cs1);                              \
    dst[2] = *(const bf16x8*)(p_ + 1 * 2048 + cs0);                              \
    dst[3] = *(const bf16x8*)(p_ + 1 * 2048 + cs1);                              \
  }
#define BAR()                          \
  {                                    \
    asm volatile("" ::: "memory");     \
    __builtin_amdgcn_s_barrier();      \
    asm volatile("" ::: "memory");     \
  }
#define MMQ(QM, QN, BREG)                                                        \
  {                                                                              \
    __builtin_amdgcn_s_setprio(1);                                               \
    _Pragma("unroll") for (int mf = 0; mf < 4; ++mf)                             \
        _Pragma("unroll") for (int nf = 0; nf < 2; ++nf)                         \
            _Pragma("unroll") for (int ks = 0; ks < 2; ++ks)                     \
                acc[(QM)*4 + mf][(QN)*2 + nf] =                                  \
        __builtin_amdgcn_mfma_f32_16x16x32_bf16(                                 \
            a[mf * 2 + ks], BREG[nf * 2 + ks], acc[(QM)*4 + mf][(QN)*2 + nf],    \
            0, 0, 0);                                                            \
    __builtin_amdgcn_s_setprio(0);                                               \
  }

  bf16x8 a[8], b0[4], b1[4];
  STG_A(0, 0, 0) STG_B(0, 0, 0) STG_A(0, 0, 1) STG_B(0, 0, 1)
  STG_A(1, 1, 0) STG_B(1, 1, 0) STG_A(1, 1, 1) STG_B(1, 1, 1)

#pragma unroll 1
  for (int kt = 0; kt < 12; ++kt) {
    const int cur = kt & 1;
    if (kt < 11) {
      asm volatile("s_waitcnt vmcnt(8)" ::: "memory");
    } else {
      asm volatile("s_waitcnt vmcnt(0)" ::: "memory");
    }
    BAR();  // BAR1
    LDA8(cur, 0)
    LDB4(b0, cur, 0)
    BAR();  // BAR2
    MMQ(0, 0, b0)
    BAR();  // BAR3
    LDB4(b1, cur, 1)
    BAR();  // BAR4
    MMQ(0, 1, b1)
    BAR();  // BAR5
    LDA8(cur, 1)
    if (kt < 10) { STG_B(cur, kt + 2, 0) STG_B(cur, kt + 2, 1) }
    BAR();  // BAR6
    MMQ(1, 1, b1)
    BAR();  // BAR7
    if (kt < 10) { STG_A(cur, kt + 2, 0) }
    BAR();  // BAR8
    MMQ(1, 0, b0)
    BAR();  // BAR9
    if (kt < 10) { STG_A(cur, kt + 2, 1) }
  }
#undef STG_A
#undef STG_B
#undef LDA8
#undef LDB4
#undef MMQ

  float br[4];
#pragma unroll
  for (int q = 0; q < 4; ++q)
    br[q] = bias[n0 + wn * 64 + (q >> 1) * 32 + (q & 1) * 16 + lr];
#pragma unroll
  for (int mh = 0; mh < 2; ++mh)
#pragma unroll
    for (int mf = 0; mf < 4; ++mf)
#pragma unroll
      for (int q = 0; q < 4; ++q)
#pragma unroll
        for (int e = 0; e < 4; ++e) {
          int m = m0 + wm * 128 + mh * 64 + mf * 16 + kb * 4 + e;
          int n = n0 + wn * 64 + (q >> 1) * 32 + (q & 1) * 16 + lr;
          if (m < 6272) out[m * 2304 + n] = acc[mh * 4 + mf][q][e] + br[q];
        }
}

extern "C" void kernel_launch(void* const* d_in, const int* in_sizes, int n_in,
                              void* d_out, int out_size, void* d_ws, size_t ws_size,
                              hipStream_t stream) {
  const float* x    = (const float*)d_in[0];
  const float* Wq   = (const float*)d_in[1];
  const float* bqkv = (const float*)d_in[2];
  const float* Aq   = (const float*)d_in[3];
  const float* Bq   = (const float*)d_in[4];
  const float* Av   = (const float*)d_in[5];
  const float* Bv   = (const float*)d_in[6];
  const float* lq   = (const float*)d_in[7];
  const float* lv   = (const float*)d_in[8];
  float* out = (float*)d_out;

  char* ws = (char*)d_ws;
  u16* xb   = (u16*)(ws + 256);              // 6400*768 bf16 (128 pad rows)
  u16* weff = (u16*)(ws + 256 + 9830400);    // 2304*768 bf16

  k_cast<<<624, 256, 0, stream>>>(x, xb, Wq, weff);
  k_dwall<<<72, 256, 0, stream>>>(Aq, Bq, Av, Bv, lq, lv, Wq, weff);
  k_gemm<<<225, 512, 0, stream>>>(xb, weff, bqkv, out);
}

// Round 10
// 149.487 us; speedup vs baseline: 1.4181x; 1.4181x over previous
//
#include <hip/hip_runtime.h>

#define TAU_INV 2.0f  // 1/0.5

typedef unsigned short u16;
typedef short bf16x8 __attribute__((ext_vector_type(8)));
typedef float f32x4 __attribute__((ext_vector_type(4)));
typedef u16 u16x4v __attribute__((ext_vector_type(4)));
typedef u16 u16x8v __attribute__((ext_vector_type(8)));

typedef __attribute__((address_space(1))) const void GASV;
typedef __attribute__((address_space(3))) void LASV;
#define GLOAD16(gp, lp) __builtin_amdgcn_global_load_lds((GASV*)(gp), (LASV*)(lp), 16, 0, 0)

__device__ __forceinline__ u16 f2bf(float f) {
  unsigned u = __float_as_uint(f);
  u += 0x7FFFu + ((u >> 16) & 1u);  // round-to-nearest-even
  return (u16)(u >> 16);
}

// ---------- kernel 1 (fused streaming): x-cast [0,588) | W mid-band [588,624) | scales [624,644) ----------
__global__ __launch_bounds__(256) void k_prep(
    const float* __restrict__ x, u16* __restrict__ xb,
    const float* __restrict__ W, u16* __restrict__ Weff,
    const float* __restrict__ Aq, const float* __restrict__ Bq,
    const float* __restrict__ Av, const float* __restrict__ Bv,
    const float* __restrict__ lq, const float* __restrict__ lv,
    float* __restrict__ scales) {
  const int bid = blockIdx.x;
  const int tid = threadIdx.x;
  if (bid < 588) {  // x f32 -> bf16
#pragma unroll
    for (int it = 0; it < 4; ++it) {
      const int i = ((bid * 4 + it) * 256 + tid) * 8;
      float4 v0 = *(const float4*)(x + i);
      float4 v1 = *(const float4*)(x + i + 4);
      u16x8v o;
      o[0] = f2bf(v0.x); o[1] = f2bf(v0.y); o[2] = f2bf(v0.z); o[3] = f2bf(v0.w);
      o[4] = f2bf(v1.x); o[5] = f2bf(v1.y); o[6] = f2bf(v1.z); o[7] = f2bf(v1.w);
      *(u16x8v*)(xb + i) = o;
    }
    return;
  }
  if (bid < 624) {  // W middle band rows 768..1535
    const int base = 589824 + (bid - 588) * 16384;
#pragma unroll
    for (int it = 0; it < 8; ++it) {
      const int i = base + (it * 256 + tid) * 8;
      float4 v0 = *(const float4*)(W + i);
      float4 v1 = *(const float4*)(W + i + 4);
      u16x8v o;
      o[0] = f2bf(v0.x); o[1] = f2bf(v0.y); o[2] = f2bf(v0.z); o[3] = f2bf(v0.w);
      o[4] = f2bf(v1.x); o[5] = f2bf(v1.y); o[6] = f2bf(v1.z); o[7] = f2bf(v1.w);
      *(u16x8v*)(Weff + i) = o;
    }
    return;
  }
  // scales: one block per (branch, task). Fully-unrolled reduction: all 24
  // loads independent and in flight (R9 lesson: rolled loop serializes).
  const int sb = bid - 624;
  const int br = sb / 10, t = sb % 10;
  const float* __restrict__ A = br ? Av : Aq;
  const float* __restrict__ B = br ? Bv : Bq;
  const float* __restrict__ lg = br ? lv : lq;
  const float4* A4 = (const float4*)(A + t * 12288);
  const float4* B4 = (const float4*)(B + t * 12288);
  float sA = 0.f, sB = 0.f;
#pragma unroll
  for (int j = 0; j < 12; ++j) {
    float4 a = A4[tid + j * 256];
    sA += a.x * a.x + a.y * a.y + a.z * a.z + a.w * a.w;
  }
#pragma unroll
  for (int j = 0; j < 12; ++j) {
    float4 v = B4[tid + j * 256];
    sB += v.x * v.x + v.y * v.y + v.z * v.z + v.w * v.w;
  }
  for (int off = 32; off; off >>= 1) {
    sA += __shfl_down(sA, off);
    sB += __shfl_down(sB, off);
  }
  __shared__ float rA[4], rB[4];
  if ((tid & 63) == 0) { rA[tid >> 6] = sA; rB[tid >> 6] = sB; }
  __syncthreads();
  if (tid == 0) {
    sA = rA[0] + rA[1] + rA[2] + rA[3];
    sB = rB[0] + rB[1] + rB[2] + rB[3];
    float mx = -1e30f;
    for (int j = 0; j < 10; ++j) mx = fmaxf(mx, lg[j] * TAU_INV);
    float den = 0.f, num = 0.f;
    for (int j = 0; j < 10; ++j) {
      float e = __expf(lg[j] * TAU_INV - mx);
      den += e;
      if (j == t) num = e;
    }
    scales[br * 16 + t] = (num / den) * rsqrtf(sA) * rsqrtf(sB);
  }
}

// ---------- kernel 2: dW bands (72 blocks), single-barrier staged MFMA ----------
// All K=160 of both operands in LDS (stride 168 kills frag conflicts),
// ~40 independent staging loads in flight, one __syncthreads, 80 MFMAs.
__global__ __launch_bounds__(256) void k_dw(
    const float* __restrict__ Aq, const float* __restrict__ Bq,
    const float* __restrict__ Av, const float* __restrict__ Bv,
    const float* __restrict__ W, const float* __restrict__ scales,
    u16* __restrict__ Weff) {
  __shared__ u16 As[128 * 168];  // [d][168]  (160 data + 8 pad)
  __shared__ u16 Bs[128 * 168];  // [c][168]
  const int bid = blockIdx.x;
  const int tid = threadIdx.x;
  const int br = bid / 36, t36 = bid % 36;
  const int tm = t36 / 6, tn = t36 % 6;
  const float* __restrict__ A = br ? Av : Aq;  // [160][768]
  const float* __restrict__ B = br ? Bv : Bq;  // [10][768][16]
  const int d0 = tm * 128, c0 = tn * 128;
  const int rowbase = br ? 1536 : 0;
  const int lane = tid & 63, w = tid >> 6, wm = w >> 1, wn = w & 1;
  const int lr = lane & 15, kb = lane >> 4;

  // stage As[d][k] = B[t][d0+d][r] * s[t],  k = t*16+r  (5120 float4s)
  for (int j = 0; j < 20; ++j) {
    int f = j * 256 + tid;
    int d = f / 40;
    int k = (f % 40) * 4;
    int t = k >> 4, r = k & 15;
    float4 v = *(const float4*)(B + (t * 768 + d0 + d) * 16 + r);
    float s = scales[br * 16 + t];
    u16x4v o;
    o[0] = f2bf(v.x * s); o[1] = f2bf(v.y * s);
    o[2] = f2bf(v.z * s); o[3] = f2bf(v.w * s);
    *(u16x4v*)(As + d * 168 + k) = o;
  }
  // stage Bs[c][k] = A[k][c0+c]  (transpose at write)
  for (int j = 0; j < 20; ++j) {
    int f = j * 256 + tid;
    int k = f / 32;
    int c = (f % 32) * 4;
    float4 v = *(const float4*)(A + k * 768 + c0 + c);
    Bs[(c + 0) * 168 + k] = f2bf(v.x);
    Bs[(c + 1) * 168 + k] = f2bf(v.y);
    Bs[(c + 2) * 168 + k] = f2bf(v.z);
    Bs[(c + 3) * 168 + k] = f2bf(v.w);
  }
  __syncthreads();

  f32x4 acc[4][4];
#pragma unroll
  for (int i = 0; i < 4; ++i)
#pragma unroll
    for (int j = 0; j < 4; ++j)
#pragma unroll
      for (int e = 0; e < 4; ++e) acc[i][j][e] = 0.f;

#pragma unroll
  for (int kt = 0; kt < 5; ++kt) {
    bf16x8 a[4], b[4];
#pragma unroll
    for (int i = 0; i < 4; ++i)
      a[i] = *(const bf16x8*)(As + (wm * 64 + i * 16 + lr) * 168 + kt * 32 + kb * 8);
#pragma unroll
    for (int j = 0; j < 4; ++j)
      b[j] = *(const bf16x8*)(Bs + (wn * 64 + j * 16 + lr) * 168 + kt * 32 + kb * 8);
#pragma unroll
    for (int i = 0; i < 4; ++i)
#pragma unroll
      for (int j = 0; j < 4; ++j)
        acc[i][j] = __builtin_amdgcn_mfma_f32_16x16x32_bf16(a[i], b[j], acc[i][j], 0, 0, 0);
  }
#pragma unroll
  for (int i = 0; i < 4; ++i)
#pragma unroll
    for (int jn = 0; jn < 4; ++jn)
#pragma unroll
      for (int j = 0; j < 4; ++j) {
        int row = rowbase + d0 + wm * 64 + i * 16 + kb * 4 + j;
        int col = c0 + wn * 64 + jn * 16 + lr;
        int g = row * 768 + col;
        Weff[g] = f2bf(W[g] + acc[i][jn][j]);
      }
}

// ---------- kernel 3: main GEMM, 256x256 8-phase (T2+T3+T4+T5), race-fixed staging ----------
// Hazard ledger (per K-tile, regions delimited by barriers):
//   B buf[cur] reads complete block-wide by BAR5 -> STG_B(cur,kt+2,*) after BAR5.
//   A buf[cur] reads complete block-wide by BAR7 -> STG_A(cur,kt+2,0) after BAR7,
//   STG_A(cur,kt+2,1) after BAR9.  vmcnt(8) at tile top forces the 8 loads
//   issued 2 iters ago complete.
__global__ __launch_bounds__(512, 2) void k_gemm(
    const u16* __restrict__ Xb,     // [6400][768] bf16 (rows >=6272 are pad)
    const u16* __restrict__ Wb,     // [2304][768] bf16
    const float* __restrict__ bias, // [2304]
    float* __restrict__ out) {      // [6272][2304]
  // bijective XCD remap: nwg=225, q=28, r=1
  const int b = blockIdx.x;
  const int xcd = b & 7, sub = b >> 3;
  const int wgid = (xcd == 0) ? sub : (29 + (xcd - 1) * 28 + sub);
  const int tn = wgid % 9, tm = wgid / 9;
  const int m0 = tm * 256, n0 = tn * 256;
  __shared__ char lds[131072];  // A: [0,64K) B: [64K,128K)
  const int tid = threadIdx.x;
  const int lane = tid & 63;
  const int w = tid >> 6, wm = w >> 2, wn = w & 3;
  const int lr = lane & 15, kb = lane >> 4;
  const int cs0 = ((kb ^ (lr & 7)) << 4);
  const int cs1 = (((4 + kb) ^ (lr & 7)) << 4);
  const int arow = (wm * 128 + lr) << 7;
  const int brow = (wn * 64 + lr) << 7;
  const int r0 = tid >> 3;
  const int cb0 = (((tid & 7) ^ (r0 & 7)) << 3);  // u16 units
  const u16* pA = Xb + (m0 + r0) * 768 + cb0;
  const u16* pB = Wb + (n0 + r0) * 768 + cb0;
  const int wb = (tid >> 6) << 10;

  f32x4 acc[8][4];
#pragma unroll
  for (int i = 0; i < 8; ++i)
#pragma unroll
    for (int j = 0; j < 4; ++j)
#pragma unroll
      for (int e = 0; e < 4; ++e) acc[i][j][e] = 0.f;

#define STG_A(buf, kt, h)                                                        \
  {                                                                              \
    GLOAD16(pA + ((h)*128 + 0) * 768 + (kt)*64, lds + (buf)*32768 + (h)*16384 + 0 + wb);    \
    GLOAD16(pA + ((h)*128 + 64) * 768 + (kt)*64, lds + (buf)*32768 + (h)*16384 + 8192 + wb);\
  }
#define STG_B(buf, kt, h)                                                        \
  {                                                                              \
    GLOAD16(pB + ((h)*128 + 0) * 768 + (kt)*64, lds + 65536 + (buf)*32768 + (h)*16384 + 0 + wb);    \
    GLOAD16(pB + ((h)*128 + 64) * 768 + (kt)*64, lds + 65536 + (buf)*32768 + (h)*16384 + 8192 + wb);\
  }
#define LDA8(buf, mh)                                                            \
  {                                                                              \
    const char* p_ = lds + (buf)*32768 + arow + (mh)*8192;                       \
    a[0] = *(const bf16x8*)(p_ + 0 * 2048 + cs0);                                \
    a[1] = *(const bf16x8*)(p_ + 0 * 2048 + cs1);                                \
    a[2] = *(const bf16x8*)(p_ + 1 * 2048 + cs0);                                \
    a[3] = *(const bf16x8*)(p_ + 1 * 2048 + cs1);                                \
    a[4] = *(const bf16x8*)(p_ + 2 * 2048 + cs0);                                \
    a[5] = *(const bf16x8*)(p_ + 2 * 2048 + cs1);                                \
    a[6] = *(const bf16x8*)(p_ + 3 * 2048 + cs0);                                \
    a[7] = *(const bf16x8*)(p_ + 3 * 2048 + cs1);                                \
  }
#define LDB4(dst, buf, nh)                                                       \
  {                                                                              \
    const char* p_ = lds + 65536 + (buf)*32768 + brow + (nh)*4096;               \
    dst[0] = *(const bf16x8*)(p_ + 0 * 2048 + cs0);                              \
    dst[1] = *(const bf16x8*)(p_ + 0 * 2048 + cs1);                              \
    dst[2] = *(const bf16x8*)(p_ + 1 * 2048 + cs0);                              \
    dst[3] = *(const bf16x8*)(p_ + 1 * 2048 + cs1);                              \
  }
#define BAR()                          \
  {                                    \
    asm volatile("" ::: "memory");     \
    __builtin_amdgcn_s_barrier();      \
    asm volatile("" ::: "memory");     \
  }
#define MMQ(QM, QN, BREG)                                                        \
  {                                                                              \
    __builtin_amdgcn_s_setprio(1);                                               \
    _Pragma("unroll") for (int mf = 0; mf < 4; ++mf)                             \
        _Pragma("unroll") for (int nf = 0; nf < 2; ++nf)                         \
            _Pragma("unroll") for (int ks = 0; ks < 2; ++ks)                     \
                acc[(QM)*4 + mf][(QN)*2 + nf] =                                  \
        __builtin_amdgcn_mfma_f32_16x16x32_bf16(                                 \
            a[mf * 2 + ks], BREG[nf * 2 + ks], acc[(QM)*4 + mf][(QN)*2 + nf],    \
            0, 0, 0);                                                            \
    __builtin_amdgcn_s_setprio(0);                                               \
  }

  bf16x8 a[8], b0[4], b1[4];
  STG_A(0, 0, 0) STG_B(0, 0, 0) STG_A(0, 0, 1) STG_B(0, 0, 1)
  STG_A(1, 1, 0) STG_B(1, 1, 0) STG_A(1, 1, 1) STG_B(1, 1, 1)

#pragma unroll 1
  for (int kt = 0; kt < 12; ++kt) {
    const int cur = kt & 1;
    if (kt < 11) {
      asm volatile("s_waitcnt vmcnt(8)" ::: "memory");
    } else {
      asm volatile("s_waitcnt vmcnt(0)" ::: "memory");
    }
    BAR();  // BAR1
    LDA8(cur, 0)
    LDB4(b0, cur, 0)
    BAR();  // BAR2
    MMQ(0, 0, b0)
    BAR();  // BAR3
    LDB4(b1, cur, 1)
    BAR();  // BAR4
    MMQ(0, 1, b1)
    BAR();  // BAR5
    LDA8(cur, 1)
    if (kt < 10) { STG_B(cur, kt + 2, 0) STG_B(cur, kt + 2, 1) }
    BAR();  // BAR6
    MMQ(1, 1, b1)
    BAR();  // BAR7
    if (kt < 10) { STG_A(cur, kt + 2, 0) }
    BAR();  // BAR8
    MMQ(1, 0, b0)
    BAR();  // BAR9
    if (kt < 10) { STG_A(cur, kt + 2, 1) }
  }
#undef STG_A
#undef STG_B
#undef LDA8
#undef LDB4
#undef MMQ

  float br[4];
#pragma unroll
  for (int q = 0; q < 4; ++q)
    br[q] = bias[n0 + wn * 64 + (q >> 1) * 32 + (q & 1) * 16 + lr];
#pragma unroll
  for (int mh = 0; mh < 2; ++mh)
#pragma unroll
    for (int mf = 0; mf < 4; ++mf)
#pragma unroll
      for (int q = 0; q < 4; ++q)
#pragma unroll
        for (int e = 0; e < 4; ++e) {
          int m = m0 + wm * 128 + mh * 64 + mf * 16 + kb * 4 + e;
          int n = n0 + wn * 64 + (q >> 1) * 32 + (q & 1) * 16 + lr;
          if (m < 6272) out[m * 2304 + n] = acc[mh * 4 + mf][q][e] + br[q];
        }
}

extern "C" void kernel_launch(void* const* d_in, const int* in_sizes, int n_in,
                              void* d_out, int out_size, void* d_ws, size_t ws_size,
                              hipStream_t stream) {
  const float* x    = (const float*)d_in[0];
  const float* Wq   = (const float*)d_in[1];
  const float* bqkv = (const float*)d_in[2];
  const float* Aq   = (const float*)d_in[3];
  const float* Bq   = (const float*)d_in[4];
  const float* Av   = (const float*)d_in[5];
  const float* Bv   = (const float*)d_in[6];
  const float* lq   = (const float*)d_in[7];
  const float* lv   = (const float*)d_in[8];
  float* out = (float*)d_out;

  char* ws = (char*)d_ws;
  float* scales = (float*)ws;                // 32 f32
  u16* xb   = (u16*)(ws + 256);              // 6400*768 bf16 (128 pad rows)
  u16* weff = (u16*)(ws + 256 + 9830400);    // 2304*768 bf16

  k_prep<<<644, 256, 0, stream>>>(x, xb, Wq, weff, Aq, Bq, Av, Bv, lq, lv, scales);
  k_dw<<<72, 256, 0, stream>>>(Aq, Bq, Av, Bv, Wq, scales, weff);
  k_gemm<<<225, 512, 0, stream>>>(xb, weff, bqkv, out);
}